// Round 4
// baseline (163.816 us; speedup 1.0000x reference)
//
#include <hip/hip_runtime.h>

// EdgewiseForcesSum: out[N,3] = segment_sum(edge_forces[E,3], edge_index[0])
// N = 100000, E = 6400000.
//
// Two-phase bucket sort (amplification-free):
//   Pass 1: read edges once, append {center,fx,fy,fz} records into 8
//           node-range buckets in d_ws (ballot-compacted, LDS-combined,
//           ~8 global tail atomics per 4096-edge block batch).
//   Pass 2: 32 blocks per bucket stream the pre-filtered records (dense,
//           coalesced int4), LDS-accumulate the 12500-node bin, flush
//           a 150 KB partial slice.
//   Pass 3: reduce the 32 partials per bin -> out.
// Fallback to the round-3 filtered single-pass kernel if ws is too small.

#define EFS_N      100000
#define EFS_E      6400000
#define EFS_NQ     (EFS_E / 4)        // 1.6M quads
#define EFS_BINS   8
#define EFS_R      12500              // nodes per bin
#define EFS_N3     (EFS_N * 3)        // 300000
#define EFS_RF     (EFS_R * 3)        // 37500 floats = 150 KB
#define EFS_CAP    816384             // records per bucket (E/8 + 16384 slack)
#define EFS_J      32                 // pass-2 blocks per bucket

#define EFS_PART_OFF  ((size_t)EFS_BINS * EFS_CAP * 16)                    // records bytes
#define EFS_TAIL_OFF  (EFS_PART_OFF + (size_t)EFS_BINS * EFS_J * EFS_RF * 4)
#define EFS_REQ       (EFS_TAIL_OFF + 64)

// ---------------- tails zero ------------------------------------------------
__global__ void efs_zero_tails(int* __restrict__ tails) {
    if (threadIdx.x < EFS_BINS) tails[threadIdx.x] = 0;
}

// ---------------- pass 1: bucketize -----------------------------------------
__global__ __launch_bounds__(1024) void efs_bucketize(
    const int4* __restrict__ ctr4,        // centers as int4 (E/4)
    const float4* __restrict__ ef4,       // forces as float4 (3E/4)
    int4* __restrict__ records,           // [BINS][CAP] 16B records
    int* __restrict__ tails) {            // [BINS]
    __shared__ int ldsCnt[EFS_BINS];
    __shared__ int ldsBase[EFS_BINS];
    const int lane = threadIdx.x & 63;
    const unsigned long long below = (1ull << lane) - 1ull;

    for (int base = blockIdx.x * blockDim.x; base < EFS_NQ;
         base += gridDim.x * blockDim.x) {
        int q = base + threadIdx.x;
        bool act = q < EFS_NQ;

        int4 cc = make_int4(0, 0, 0, 0);
        float4 fa = make_float4(0, 0, 0, 0), fb = fa, fd = fa;
        if (act) {
            cc = ctr4[q];
            fa = ef4[3 * q + 0];   // e0.x e0.y e0.z e1.x
            fb = ef4[3 * q + 1];   // e1.y e1.z e2.x e2.y
            fd = ef4[3 * q + 2];   // e2.z e3.x e3.y e3.z
        }
        int c_[4] = {cc.x, cc.y, cc.z, cc.w};
        int bk[4], off[4];
        #pragma unroll
        for (int k = 0; k < 4; k++) {
            bk[k] = act ? (c_[k] / EFS_R) : EFS_BINS;   // inactive -> no bucket
            off[k] = 0;
        }

        if (threadIdx.x < EFS_BINS) ldsCnt[threadIdx.x] = 0;
        __syncthreads();

        // wave-level compaction: per edge-slot k, per bucket b
        #pragma unroll
        for (int k = 0; k < 4; k++) {
            for (int b = 0; b < EFS_BINS; b++) {
                unsigned long long m = __ballot(bk[k] == b);
                if (m) {  // wave-uniform
                    int leader = __ffsll((long long)m) - 1;
                    int w = 0;
                    if (lane == leader)
                        w = atomicAdd(&ldsCnt[b], (int)__popcll(m));
                    w = __shfl(w, leader);
                    if (bk[k] == b)
                        off[k] = w + (int)__popcll(m & below);
                }
            }
        }
        __syncthreads();
        if (threadIdx.x < EFS_BINS)
            ldsBase[threadIdx.x] =
                atomicAdd(&tails[threadIdx.x], ldsCnt[threadIdx.x]);
        __syncthreads();

        float fx[4] = {fa.x, fa.w, fb.z, fd.y};
        float fy[4] = {fa.y, fb.x, fb.w, fd.z};
        float fz[4] = {fa.z, fb.y, fd.x, fd.w};
        #pragma unroll
        for (int k = 0; k < 4; k++) {
            if (bk[k] < EFS_BINS) {
                long slot = (long)ldsBase[bk[k]] + off[k];
                if (slot >= 0 && slot < EFS_CAP)
                    records[(size_t)bk[k] * EFS_CAP + slot] =
                        make_int4(c_[k], __float_as_int(fx[k]),
                                  __float_as_int(fy[k]), __float_as_int(fz[k]));
            }
        }
        __syncthreads();  // protect ldsBase until all stores done
    }
}

// ---------------- pass 2: dense accumulate ----------------------------------
__global__ __launch_bounds__(1024) void efs_accum(
    const int4* __restrict__ records, const int* __restrict__ tails,
    float* __restrict__ partials) {
    __shared__ float lds[EFS_RF];
    int b = blockIdx.x / EFS_J;
    int j = blockIdx.x % EFS_J;

    float4* lds4 = (float4*)lds;
    for (int i = threadIdx.x; i < EFS_RF / 4; i += blockDim.x)
        lds4[i] = make_float4(0.f, 0.f, 0.f, 0.f);
    __syncthreads();

    int cnt = tails[b];
    if (cnt > EFS_CAP) cnt = EFS_CAP;
    int r0 = (int)((long)j * cnt / EFS_J);
    int r1 = (int)((long)(j + 1) * cnt / EFS_J);
    const int4* rec = records + (size_t)b * EFS_CAP;
    const int binStart = b * EFS_R;

    for (int r = r0 + threadIdx.x; r < r1; r += blockDim.x) {
        int4 e = rec[r];
        int rel = e.x - binStart;
        atomicAdd(&lds[rel * 3 + 0], __int_as_float(e.y));
        atomicAdd(&lds[rel * 3 + 1], __int_as_float(e.z));
        atomicAdd(&lds[rel * 3 + 2], __int_as_float(e.w));
    }
    __syncthreads();

    float4* dst = (float4*)(partials + (size_t)blockIdx.x * EFS_RF);
    for (int i = threadIdx.x; i < EFS_RF / 4; i += blockDim.x)
        dst[i] = lds4[i];
}

// ---------------- pass 3: reduce partials -> out ----------------------------
__global__ void efs_reduce(const float4* __restrict__ partials,
                           float4* __restrict__ out) {
    int i4 = blockIdx.x * blockDim.x + threadIdx.x;
    if (i4 >= EFS_N3 / 4) return;
    int f = i4 * 4;
    int b = f / EFS_RF;                     // bin
    int o4 = (f - b * EFS_RF) >> 2;         // float4 offset within slice
    const float4* base = partials + (size_t)b * EFS_J * (EFS_RF / 4) + o4;
    float4 s = base[0];
    #pragma unroll
    for (int j = 1; j < EFS_J; j++) {
        float4 v = base[(size_t)j * (EFS_RF / 4)];
        s.x += v.x; s.y += v.y; s.z += v.z; s.w += v.w;
    }
    out[i4] = s;
}

// ---------------- fallback: round-3 filtered single pass --------------------
__global__ __launch_bounds__(1024) void efs_bin_kernel(
    const int4* __restrict__ ctr4, const float4* __restrict__ ef4,
    float* __restrict__ partials, int P) {
    __shared__ float lds[EFS_RF];
    int c = blockIdx.x % P;
    int b = blockIdx.x / P;
    float4* lds4 = (float4*)lds;
    for (int i = threadIdx.x; i < EFS_RF / 4; i += blockDim.x)
        lds4[i] = make_float4(0.f, 0.f, 0.f, 0.f);
    __syncthreads();
    const int binStart = b * EFS_R;
    const int q0 = (int)((long)c * EFS_E / P) / 4;
    const int q1 = (int)((long)(c + 1) * EFS_E / P) / 4;
    #pragma unroll 2
    for (int q = q0 + threadIdx.x; q < q1; q += blockDim.x) {
        int4 cc = ctr4[q];
        float4 fa = ef4[3 * q + 0];
        float4 fb = ef4[3 * q + 1];
        float4 fd = ef4[3 * q + 2];
        unsigned r0 = (unsigned)(cc.x - binStart);
        unsigned r1 = (unsigned)(cc.y - binStart);
        unsigned r2 = (unsigned)(cc.z - binStart);
        unsigned r3 = (unsigned)(cc.w - binStart);
        if (r0 < (unsigned)EFS_R) {
            atomicAdd(&lds[r0 * 3 + 0], fa.x);
            atomicAdd(&lds[r0 * 3 + 1], fa.y);
            atomicAdd(&lds[r0 * 3 + 2], fa.z);
        }
        if (r1 < (unsigned)EFS_R) {
            atomicAdd(&lds[r1 * 3 + 0], fa.w);
            atomicAdd(&lds[r1 * 3 + 1], fb.x);
            atomicAdd(&lds[r1 * 3 + 2], fb.y);
        }
        if (r2 < (unsigned)EFS_R) {
            atomicAdd(&lds[r2 * 3 + 0], fb.z);
            atomicAdd(&lds[r2 * 3 + 1], fb.w);
            atomicAdd(&lds[r2 * 3 + 2], fd.x);
        }
        if (r3 < (unsigned)EFS_R) {
            atomicAdd(&lds[r3 * 3 + 0], fd.y);
            atomicAdd(&lds[r3 * 3 + 1], fd.z);
            atomicAdd(&lds[r3 * 3 + 2], fd.w);
        }
    }
    __syncthreads();
    float4* dst = (float4*)(partials + (size_t)c * EFS_N3 + (size_t)binStart * 3);
    for (int i = threadIdx.x; i < EFS_RF / 4; i += blockDim.x)
        dst[i] = lds4[i];
}

__global__ void efs_reduce_kernel(const float4* __restrict__ partials,
                                  float4* __restrict__ out, int P) {
    const int n4 = EFS_N3 / 4;
    int i = blockIdx.x * blockDim.x + threadIdx.x;
    if (i >= n4) return;
    float4 s = partials[i];
    for (int p = 1; p < P; ++p) {
        float4 v = partials[(size_t)p * n4 + i];
        s.x += v.x; s.y += v.y; s.z += v.z; s.w += v.w;
    }
    out[i] = s;
}

__global__ void efs_zero_kernel(float* __restrict__ out, int n) {
    int i = blockIdx.x * blockDim.x + threadIdx.x;
    if (i < n) out[i] = 0.0f;
}

__global__ void efs_scatter_kernel(const float4* __restrict__ ef4,
                                   const int4* __restrict__ ctr4,
                                   float* __restrict__ out, int n_quads) {
    int t = blockIdx.x * blockDim.x + threadIdx.x;
    if (t >= n_quads) return;
    int4 c = ctr4[t];
    float4 a = ef4[t * 3 + 0];
    float4 b = ef4[t * 3 + 1];
    float4 d = ef4[t * 3 + 2];
    atomicAdd(&out[c.x * 3 + 0], a.x);
    atomicAdd(&out[c.x * 3 + 1], a.y);
    atomicAdd(&out[c.x * 3 + 2], a.z);
    atomicAdd(&out[c.y * 3 + 0], a.w);
    atomicAdd(&out[c.y * 3 + 1], b.x);
    atomicAdd(&out[c.y * 3 + 2], b.y);
    atomicAdd(&out[c.z * 3 + 0], b.z);
    atomicAdd(&out[c.z * 3 + 1], b.w);
    atomicAdd(&out[c.z * 3 + 2], d.x);
    atomicAdd(&out[c.w * 3 + 0], d.y);
    atomicAdd(&out[c.w * 3 + 1], d.z);
    atomicAdd(&out[c.w * 3 + 2], d.w);
}

extern "C" void kernel_launch(void* const* d_in, const int* in_sizes, int n_in,
                              void* d_out, int out_size, void* d_ws, size_t ws_size,
                              hipStream_t stream) {
    const float* edge_forces = (const float*)d_in[0];
    const int*   edge_index  = (const int*)d_in[1];   // row 0 = centers
    float*       out         = (float*)d_out;
    const int E = in_sizes[1] / 2;

    if (ws_size >= EFS_REQ) {
        int4*  records  = (int4*)d_ws;
        float* partials = (float*)((char*)d_ws + EFS_PART_OFF);
        int*   tails    = (int*)((char*)d_ws + EFS_TAIL_OFF);

        efs_zero_tails<<<1, 64, 0, stream>>>(tails);
        efs_bucketize<<<512, 1024, 0, stream>>>(
            (const int4*)edge_index, (const float4*)edge_forces, records, tails);
        efs_accum<<<EFS_BINS * EFS_J, 1024, 0, stream>>>(records, tails, partials);
        int n4 = EFS_N3 / 4;
        efs_reduce<<<(n4 + 255) / 256, 256, 0, stream>>>(
            (const float4*)partials, (float4*)out);
        return;
    }

    // ---- fallback paths ----
    int P = (int)(ws_size / ((size_t)EFS_N3 * sizeof(float)));
    if (P > 32) P = 32;
    if (P >= 1) {
        float* partials = (float*)d_ws;
        efs_bin_kernel<<<dim3(EFS_BINS * P), 1024, 0, stream>>>(
            (const int4*)edge_index, (const float4*)edge_forces, partials, P);
        int n4 = EFS_N3 / 4;
        efs_reduce_kernel<<<(n4 + 255) / 256, 256, 0, stream>>>(
            (const float4*)partials, (float4*)out, P);
    } else {
        int threads = 256;
        int blocks = (out_size + threads - 1) / threads;
        efs_zero_kernel<<<blocks, threads, 0, stream>>>(out, out_size);
        int n_quads = E / 4;
        blocks = (n_quads + threads - 1) / threads;
        efs_scatter_kernel<<<blocks, threads, 0, stream>>>(
            (const float4*)edge_forces, (const int4*)edge_index, out, n_quads);
    }
}

// Round 5
// 124.493 us; speedup vs baseline: 1.3159x; 1.3159x over previous
//
#include <hip/hip_runtime.h>

// EdgewiseForcesSum: out[N,3] = segment_sum(edge_forces[E,3], edge_index[0])
// N = 100000, E = 6400000.
// Round-3 single-pass binned structure, with unsafeAtomicAdd (native
// ds_add_f32 / global_atomic_add_f32) instead of HIP's default CAS-loop
// float atomics. 8 bins x 12500 nodes; block (bin b, chunk c) streams its
// 200K-edge chunk with unconditional vectorized loads, accumulates matches
// into a 150 KB LDS bin, flushes to partial c in d_ws; phase 2 reduces.

#define EFS_N      100000
#define EFS_E      6400000
#define EFS_BINS   8
#define EFS_R      12500          // nodes per bin
#define EFS_MAXP   32
#define EFS_N3     (EFS_N * 3)    // 300000
#define EFS_RF     (EFS_R * 3)    // 37500 floats = 150 KB

__device__ __forceinline__ void efs_fadd(float* p, float v) {
#if defined(__HIP_DEVICE_COMPILE__)
    unsafeAtomicAdd(p, v);        // native HW fp32 atomic add
#else
    atomicAdd(p, v);
#endif
}

// ---------------- phase 1: bin + LDS accumulate + stream flush --------------
__global__ __launch_bounds__(1024) void efs_bin_kernel(
    const int4* __restrict__ ctr4,        // centers as int4 (E/4)
    const float4* __restrict__ ef4,       // forces as float4 (3E/4)
    float* __restrict__ partials,         // P x N3 floats in d_ws
    int P) {
    __shared__ float lds[EFS_RF];

    int c = blockIdx.x % P;               // chunk id  (c%8 selects XCD)
    int b = blockIdx.x / P;               // bin id

    float4* lds4 = (float4*)lds;
    for (int i = threadIdx.x; i < EFS_RF / 4; i += blockDim.x)
        lds4[i] = make_float4(0.f, 0.f, 0.f, 0.f);
    __syncthreads();

    const int binStart = b * EFS_R;
    const int q0 = (int)((long)c * EFS_E / P) / 4;        // quad range
    const int q1 = (int)((long)(c + 1) * EFS_E / P) / 4;

    #pragma unroll 2
    for (int q = q0 + threadIdx.x; q < q1; q += blockDim.x) {
        // 4 edges: all loads independent, issued before any use
        int4   cc = ctr4[q];
        float4 fa = ef4[3 * q + 0];   // e0.x e0.y e0.z e1.x
        float4 fb = ef4[3 * q + 1];   // e1.y e1.z e2.x e2.y
        float4 fd = ef4[3 * q + 2];   // e2.z e3.x e3.y e3.z

        unsigned r0 = (unsigned)(cc.x - binStart);
        unsigned r1 = (unsigned)(cc.y - binStart);
        unsigned r2 = (unsigned)(cc.z - binStart);
        unsigned r3 = (unsigned)(cc.w - binStart);

        if (r0 < (unsigned)EFS_R) {
            efs_fadd(&lds[r0 * 3 + 0], fa.x);
            efs_fadd(&lds[r0 * 3 + 1], fa.y);
            efs_fadd(&lds[r0 * 3 + 2], fa.z);
        }
        if (r1 < (unsigned)EFS_R) {
            efs_fadd(&lds[r1 * 3 + 0], fa.w);
            efs_fadd(&lds[r1 * 3 + 1], fb.x);
            efs_fadd(&lds[r1 * 3 + 2], fb.y);
        }
        if (r2 < (unsigned)EFS_R) {
            efs_fadd(&lds[r2 * 3 + 0], fb.z);
            efs_fadd(&lds[r2 * 3 + 1], fb.w);
            efs_fadd(&lds[r2 * 3 + 2], fd.x);
        }
        if (r3 < (unsigned)EFS_R) {
            efs_fadd(&lds[r3 * 3 + 0], fd.y);
            efs_fadd(&lds[r3 * 3 + 1], fd.z);
            efs_fadd(&lds[r3 * 3 + 2], fd.w);
        }
    }
    __syncthreads();

    float4* dst = (float4*)(partials + (size_t)c * EFS_N3 + (size_t)binStart * 3);
    for (int i = threadIdx.x; i < EFS_RF / 4; i += blockDim.x)
        dst[i] = lds4[i];
}

// ---------------- phase 2: reduce P partials -> out -------------------------
__global__ void efs_reduce_kernel(const float4* __restrict__ partials,
                                  float4* __restrict__ out, int P) {
    const int n4 = EFS_N3 / 4;            // 75000
    int i = blockIdx.x * blockDim.x + threadIdx.x;
    if (i >= n4) return;
    float4 s = partials[i];
    for (int p = 1; p < P; ++p) {
        float4 v = partials[(size_t)p * n4 + i];
        s.x += v.x; s.y += v.y; s.z += v.z; s.w += v.w;
    }
    out[i] = s;
}

// ---------------- fallback (tiny ws): atomic scatter ------------------------
__global__ void efs_zero_kernel(float* __restrict__ out, int n) {
    int i = blockIdx.x * blockDim.x + threadIdx.x;
    if (i < n) out[i] = 0.0f;
}

__global__ void efs_scatter_kernel(const float4* __restrict__ ef4,
                                   const int4* __restrict__ ctr4,
                                   float* __restrict__ out, int n_quads) {
    int t = blockIdx.x * blockDim.x + threadIdx.x;
    if (t >= n_quads) return;
    int4 c = ctr4[t];
    float4 a = ef4[t * 3 + 0];
    float4 b = ef4[t * 3 + 1];
    float4 d = ef4[t * 3 + 2];
    efs_fadd(&out[c.x * 3 + 0], a.x);
    efs_fadd(&out[c.x * 3 + 1], a.y);
    efs_fadd(&out[c.x * 3 + 2], a.z);
    efs_fadd(&out[c.y * 3 + 0], a.w);
    efs_fadd(&out[c.y * 3 + 1], b.x);
    efs_fadd(&out[c.y * 3 + 2], b.y);
    efs_fadd(&out[c.z * 3 + 0], b.z);
    efs_fadd(&out[c.z * 3 + 1], b.w);
    efs_fadd(&out[c.z * 3 + 2], d.x);
    efs_fadd(&out[c.w * 3 + 0], d.y);
    efs_fadd(&out[c.w * 3 + 1], d.z);
    efs_fadd(&out[c.w * 3 + 2], d.w);
}

extern "C" void kernel_launch(void* const* d_in, const int* in_sizes, int n_in,
                              void* d_out, int out_size, void* d_ws, size_t ws_size,
                              hipStream_t stream) {
    const float* edge_forces = (const float*)d_in[0];
    const int*   edge_index  = (const int*)d_in[1];   // row 0 = centers
    float*       out         = (float*)d_out;

    const int E = in_sizes[1] / 2;

    int P = (int)(ws_size / ((size_t)EFS_N3 * sizeof(float)));
    if (P > EFS_MAXP) P = EFS_MAXP;

    if (P >= 1) {
        float* partials = (float*)d_ws;
        dim3 grid1(EFS_BINS * P);
        efs_bin_kernel<<<grid1, 1024, 0, stream>>>(
            (const int4*)edge_index, (const float4*)edge_forces, partials, P);
        int n4 = EFS_N3 / 4;
        int threads = 256;
        int blocks = (n4 + threads - 1) / threads;
        efs_reduce_kernel<<<blocks, threads, 0, stream>>>((const float4*)partials,
                                                          (float4*)out, P);
    } else {
        int threads = 256;
        int blocks = (out_size + threads - 1) / threads;
        efs_zero_kernel<<<blocks, threads, 0, stream>>>(out, out_size);
        int n_quads = E / 4;
        blocks = (n_quads + threads - 1) / threads;
        efs_scatter_kernel<<<blocks, threads, 0, stream>>>(
            (const float4*)edge_forces, (const int4*)edge_index, out, n_quads);
    }
}